// Round 8
// baseline (142.517 us; speedup 1.0000x reference)
//
#include <hip/hip_runtime.h>

#define N 8192

typedef __attribute__((ext_vector_type(8))) short short8;
typedef __attribute__((ext_vector_type(4))) float f32x4;
typedef __attribute__((ext_vector_type(2))) float f32x2;

#define ADJ_SC 4096.0f
#define ADJ_ISC (1.0f / 4096.0f)

__device__ __forceinline__ unsigned short f2bf(float f) {
    union { float f; unsigned int u; } v; v.f = f;
    unsigned int r = v.u + 0x7FFFu + ((v.u >> 16) & 1u);  // round-to-nearest-even
    return (unsigned short)(r >> 16);
}

__device__ __forceinline__ float bf2f(unsigned short u) {
    return __builtin_bit_cast(float, (unsigned int)u << 16);
}

__device__ __forceinline__ void gl2lds16(const void* g, void* l) {
    __builtin_amdgcn_global_load_lds(
        (const __attribute__((address_space(1))) unsigned int*)g,
        (__attribute__((address_space(3))) unsigned int*)l, 16, 0, 0);
}

// 8 fp8-e4m3 bytes -> 8 bf16 (lossless: every e4m3 value is exactly a bf16)
__device__ __forceinline__ short8 fp8x8_to_bf16x8(uint2 a8) {
    short8 r;
    #pragma unroll
    for (int d = 0; d < 2; ++d) {
        unsigned int src = (d == 0) ? a8.x : a8.y;
        f32x2 lo = __builtin_amdgcn_cvt_pk_f32_fp8(src, false);
        f32x2 hi = __builtin_amdgcn_cvt_pk_f32_fp8(src, true);
        r[4 * d + 0] = (short)(__builtin_bit_cast(unsigned int, lo[0]) >> 16);
        r[4 * d + 1] = (short)(__builtin_bit_cast(unsigned int, lo[1]) >> 16);
        r[4 * d + 2] = (short)(__builtin_bit_cast(unsigned int, hi[0]) >> 16);
        r[4 * d + 3] = (short)(__builtin_bit_cast(unsigned int, hi[1]) >> 16);
    }
    return r;
}

#define BAR_SCHED() do { __builtin_amdgcn_s_barrier(); \
                         __builtin_amdgcn_sched_barrier(0); } while (0)

// ---------------------------------------------------------------------------
// Aggregation: y_part[ks] = adj[rows, kslice] @ h   (partials stored bf16)
// MODE 0: adj f32 (no writeback)     [BK=64, counted-vmcnt reg prefetch]
// MODE 1: adj f32 + pre-swizzled fp8-e4m3 writeback (adj*4096)  [BK=64]
// MODE 2: linear gl2lds of pre-swizzled fp8 adj (BK=64), double-buffered,
//   lossless fp8->bf16 expand in regs, bf16 MFMA, acc *= 2^-12 at epilogue.
// hT stored PRE-SWIZZLED (elem ^ ((c&7)<<3)); adj_b pre-swizzled within
// 64-B k-chunks (byte ^ ((row&7)<<3)). LDS fragment reads apply same XOR.
// BM=64 rows, 4 waves, wave w -> rows [16w,16w+16).
// ---------------------------------------------------------------------------
template<int NC, int BK, int MODE>
__global__ __launch_bounds__(256) void agg_kernel(
    const float* __restrict__ adj,
    const unsigned char* __restrict__ adj_b_in,
    unsigned char* __restrict__ adj_b_out,
    const unsigned short* __restrict__ hT,   // [NC][N] bf16, pre-swizzled
    unsigned short* __restrict__ y,          // [S][N][NC] bf16 partials
    int klen)
{
    constexpr int BM = 64;
    constexpr int NCT = NC / 16;

    const int tid = threadIdx.x;
    const int w  = tid >> 6;
    const int l  = tid & 63;
    const int hi = l >> 4;
    const int lr = l & 15;
    const int row0 = blockIdx.x * BM;
    const int k00  = blockIdx.y * klen;
    const int nt   = klen / BK;

    f32x4 acc[NCT];
    #pragma unroll
    for (int i = 0; i < NCT; ++i) acc[i] = f32x4{0.f, 0.f, 0.f, 0.f};

    if constexpr (MODE == 2) {
        // fp8 adj tile: BK bytes/row; bf16 hT tile: 2*BK bytes/row
        __shared__ unsigned char as2_[2][BM * BK];
        __shared__ unsigned short hs2_[2][NC * BK];
        constexpr int TA = (BM * BK) / 1024;       // 1KB chunks, adj tile
        constexpr int TH = (NC * 2 * BK) / 1024;   // 1KB chunks, hT tile
        constexpr int GRA = BK / 16, RPA = 1024 / BK;
        constexpr int GRH = (2 * BK) / 16, RPH = 1024 / (2 * BK);
        constexpr int KW = (TA + TH) / 4;          // per-wave gl2lds per stage

        auto stage = [&](char* ab, char* hb, int t) {
            const int kb = k00 + t * BK;
            #pragma unroll
            for (int i = w; i < TA; i += 4) {
                int r = i * RPA + l / GRA, g = l % GRA;
                gl2lds16(adj_b_in + (size_t)(row0 + r) * N + kb + 16 * g,
                         ab + i * 1024);
            }
            #pragma unroll
            for (int i = w; i < TH; i += 4) {
                int c = i * RPH + l / GRH, g = l % GRH;
                gl2lds16(hT + (size_t)c * N + kb + 8 * g, hb + i * 1024);
            }
        };

        stage((char*)as2_[0], (char*)hs2_[0], 0);
        for (int t = 0; t < nt; ++t) {
            char* ca = (char*)as2_[t & 1];
            char* ch = (char*)hs2_[t & 1];
            char* na = (char*)as2_[(t & 1) ^ 1];
            char* nh = (char*)hs2_[(t & 1) ^ 1];
            if (t + 1 < nt) {
                stage(na, nh, t + 1);
                asm volatile("s_waitcnt vmcnt(%0)" :: "n"(KW) : "memory");
            } else {
                asm volatile("s_waitcnt vmcnt(0)" ::: "memory");
            }
            BAR_SCHED();
            #pragma unroll
            for (int kk = 0; kk < BK; kk += 32) {
                const int arow = 16 * w + lr;
                uint2 a8 = *reinterpret_cast<const uint2*>(
                    ca + arow * BK + ((kk + 8 * hi) ^ ((arow & 7) << 3)));
                short8 a = fp8x8_to_bf16x8(a8);
                #pragma unroll
                for (int ct = 0; ct < NCT; ++ct) {
                    const int bcol = 16 * ct + lr;
                    short8 b = *reinterpret_cast<const short8*>(
                        ch + bcol * (2 * BK) + ((2 * kk + 16 * hi) ^ ((bcol & 7) << 4)));
                    acc[ct] = __builtin_amdgcn_mfma_f32_16x16x32_bf16(a, b, acc[ct], 0, 0, 0);
                }
            }
            asm volatile("s_waitcnt lgkmcnt(0)" ::: "memory");
            BAR_SCHED();
        }
        #pragma unroll
        for (int ct = 0; ct < NCT; ++ct)
            #pragma unroll
            for (int r = 0; r < 4; ++r) acc[ct][r] *= ADJ_ISC;
    } else {
        // MODE 0/1: BK==64. Counted-vmcnt reg-prefetch pipeline, 10KB LDS.
        __shared__ unsigned short as_[BM * BK];
        __shared__ unsigned short hs_[NC * BK];
        char* asb = (char*)as_;
        char* hsb = (char*)hs_;
        constexpr int ROWB = BK * 2;               // 128 B LDS rows
        constexpr int LV = (BM * BK) / (4 * 256);  // 4 float4 per thread
        constexpr int GQ = BK / 4;                 // float4 groups per row
        constexpr int TH = (NC * ROWB) / 1024;     // hT 1KB chunks
        constexpr int RPH = 1024 / ROWB;           // hT rows per chunk
        constexpr int GRH = ROWB / 16;             // 16B granules per hT row
        float4 pf[LV];
        #pragma unroll
        for (int it = 0; it < LV; ++it) {
            int idx = tid + it * 256, r = idx / GQ, q = idx % GQ;
            const f32x4* p = reinterpret_cast<const f32x4*>(
                adj + (size_t)(row0 + r) * N + k00 + 4 * q);
            f32x4 t0 = __builtin_nontemporal_load(p);
            pf[it] = float4{t0[0], t0[1], t0[2], t0[3]};
        }
        for (int t = 0; t < nt; ++t) {
            const int kb = k00 + t * BK;
            // (1) hT tile: linear gl2lds (content pre-swizzled)  [oldest]
            #pragma unroll
            for (int i = w; i < TH; i += 4) {
                int c = i * RPH + l / GRH, g = l % GRH;
                gl2lds16(hT + (size_t)c * N + kb + 8 * g, hsb + i * 1024);
            }
            __builtin_amdgcn_sched_barrier(0);
            // (2) convert + fp8 writeback store + swizzled bf16 LDS write
            #pragma unroll
            for (int it = 0; it < LV; ++it) {
                int idx = tid + it * 256, r = idx / GQ, q = idx % GQ;
                ushort4 u;
                u.x = f2bf(pf[it].x); u.y = f2bf(pf[it].y);
                u.z = f2bf(pf[it].z); u.w = f2bf(pf[it].w);
                if (MODE == 1) {
                    unsigned int pk = 0;
                    pk = __builtin_amdgcn_cvt_pk_fp8_f32(
                        pf[it].x * ADJ_SC, pf[it].y * ADJ_SC, pk, false);
                    pk = __builtin_amdgcn_cvt_pk_fp8_f32(
                        pf[it].z * ADJ_SC, pf[it].w * ADJ_SC, pk, true);
                    *reinterpret_cast<unsigned int*>(
                        adj_b_out + (size_t)(row0 + r) * N + kb +
                        ((4 * q) ^ ((r & 7) << 3))) = pk;
                }
                *reinterpret_cast<ushort4*>(
                    asb + r * ROWB + ((8 * q) ^ ((r & 7) << 4))) = u;
            }
            __builtin_amdgcn_sched_barrier(0);
            // (3) next-tile prefetch [newest, stays in flight across barriers]
            if (t + 1 < nt) {
                #pragma unroll
                for (int it = 0; it < LV; ++it) {
                    int idx = tid + it * 256, r = idx / GQ, q = idx % GQ;
                    const f32x4* p = reinterpret_cast<const f32x4*>(
                        adj + (size_t)(row0 + r) * N + kb + BK + 4 * q);
                    f32x4 t0 = __builtin_nontemporal_load(p);
                    pf[it] = float4{t0[0], t0[1], t0[2], t0[3]};
                }
                __builtin_amdgcn_sched_barrier(0);
                // drain gl2lds(t); keep stores(4)+loads(4) in flight
                if (MODE == 1)
                    asm volatile("s_waitcnt vmcnt(8) lgkmcnt(0)" ::: "memory");
                else
                    asm volatile("s_waitcnt vmcnt(4) lgkmcnt(0)" ::: "memory");
            } else {
                if (MODE == 1)
                    asm volatile("s_waitcnt vmcnt(4) lgkmcnt(0)" ::: "memory");
                else
                    asm volatile("s_waitcnt vmcnt(0) lgkmcnt(0)" ::: "memory");
            }
            BAR_SCHED();
            // (4) MFMA phase
            #pragma unroll
            for (int kk = 0; kk < BK; kk += 32) {
                const int arow = 16 * w + lr;
                short8 a = *reinterpret_cast<const short8*>(
                    asb + arow * ROWB + ((2 * kk + 16 * hi) ^ ((arow & 7) << 4)));
                #pragma unroll
                for (int ct = 0; ct < NCT; ++ct) {
                    const int bcol = 16 * ct + lr;
                    short8 b = *reinterpret_cast<const short8*>(
                        hsb + bcol * ROWB + ((2 * kk + 16 * hi) ^ ((bcol & 7) << 4)));
                    acc[ct] = __builtin_amdgcn_mfma_f32_16x16x32_bf16(a, b, acc[ct], 0, 0, 0);
                }
            }
            asm volatile("s_waitcnt lgkmcnt(0)" ::: "memory");
            BAR_SCHED();
        }
    }
    // write bf16 partials: D layout col=lane&15, row=4*(lane>>4)+reg
    unsigned short* yp = y + (size_t)blockIdx.y * N * NC;
    #pragma unroll
    for (int ct = 0; ct < NCT; ++ct) {
        #pragma unroll
        for (int r = 0; r < 4; ++r) {
            yp[(size_t)(row0 + 16 * w + 4 * hi + r) * NC + 16 * ct + lr] =
                f2bf(acc[ct][r]);
        }
    }
}

// ---------------------------------------------------------------------------
// lin0: hT = bf16((x @ W0 + b0)^T), pre-swizzled columns
// ---------------------------------------------------------------------------
__global__ __launch_bounds__(256) void lin0_kernel(
    const float* __restrict__ x, const float* __restrict__ W,
    const float* __restrict__ b, unsigned short* __restrict__ hT)
{
    __shared__ float xs[64][129];
    const int tid = threadIdx.x;
    const int row0 = blockIdx.x * 64;
    #pragma unroll
    for (int it = 0; it < 8; ++it) {
        int idx = tid + it * 256;
        int r = idx >> 5, q = idx & 31;
        float4 v = *reinterpret_cast<const float4*>(x + (size_t)(row0 + r) * 128 + 4 * q);
        xs[r][4 * q + 0] = v.x; xs[r][4 * q + 1] = v.y;
        xs[r][4 * q + 2] = v.z; xs[r][4 * q + 3] = v.w;
    }
    __syncthreads();
    const int w = tid >> 6, l = tid & 63;
    float acc[4] = {b[w], b[w + 4], b[w + 8], b[w + 12]};
    for (int k = 0; k < 128; ++k) {
        float xv = xs[l][k];
        #pragma unroll
        for (int cc = 0; cc < 4; ++cc) acc[cc] += xv * W[k * 16 + w + 4 * cc];
    }
    #pragma unroll
    for (int cc = 0; cc < 4; ++cc) {
        int c = w + 4 * cc;
        hT[(size_t)c * N + ((row0 + l) ^ ((c & 7) << 3))] = f2bf(acc[cc]);
    }
}

// ---------------------------------------------------------------------------
// mid linear: hT = bf16((relu(sum_s y_s) @ W + b)^T), pre-swizzled columns
// y input is bf16 partials.
// ---------------------------------------------------------------------------
template<int NIN, int NOUT, int S>
__global__ __launch_bounds__(256) void mid_linear_kernel(
    const unsigned short* __restrict__ y,  // [S][N][NIN] bf16
    const float* __restrict__ W,           // [NIN][NOUT]
    const float* __restrict__ b,
    unsigned short* __restrict__ hT)       // [NOUT][N]
{
    __shared__ float xs[64][NIN + 1];
    const int tid = threadIdx.x;
    const int row0 = blockIdx.x * 64;
    constexpr int NF4 = 64 * NIN / 4;
    #pragma unroll
    for (int idx0 = 0; idx0 < NF4; idx0 += 256) {
        int idx = idx0 + tid;
        if (NF4 >= 256 || idx < NF4) {
            int r = idx / (NIN / 4), q = idx % (NIN / 4);
            size_t off = (size_t)(row0 + r) * NIN + 4 * q;
            float s0 = 0.f, s1 = 0.f, s2 = 0.f, s3 = 0.f;
            #pragma unroll
            for (int s = 0; s < S; ++s) {
                ushort4 t = *reinterpret_cast<const ushort4*>(
                    y + (size_t)s * N * NIN + off);
                s0 += bf2f(t.x); s1 += bf2f(t.y);
                s2 += bf2f(t.z); s3 += bf2f(t.w);
            }
            xs[r][4 * q + 0] = fmaxf(s0, 0.f);
            xs[r][4 * q + 1] = fmaxf(s1, 0.f);
            xs[r][4 * q + 2] = fmaxf(s2, 0.f);
            xs[r][4 * q + 3] = fmaxf(s3, 0.f);
        }
    }
    __syncthreads();
    const int w = tid >> 6, l = tid & 63;
    constexpr int CC = NOUT / 4;
    float acc[CC];
    #pragma unroll
    for (int cc = 0; cc < CC; ++cc) acc[cc] = b[w + 4 * cc];
    for (int k = 0; k < NIN; ++k) {
        float xv = xs[l][k];
        #pragma unroll
        for (int cc = 0; cc < CC; ++cc) acc[cc] += xv * W[k * NOUT + w + 4 * cc];
    }
    #pragma unroll
    for (int cc = 0; cc < CC; ++cc) {
        int c = w + 4 * cc;
        hT[(size_t)c * N + ((row0 + l) ^ ((c & 7) << 3))] = f2bf(acc[cc]);
    }
}

// ---------------------------------------------------------------------------
// head: out = relu(relu(sum_s y_s) @ Wo0 + bo0) @ Wo1 + bo1, 16 rows/block
// y input bf16.
// ---------------------------------------------------------------------------
template<int S>
__global__ __launch_bounds__(256) void head_kernel(
    const unsigned short* __restrict__ y,  // [S][N][64] bf16
    const float* __restrict__ Wo0, const float* __restrict__ bo0,
    const float* __restrict__ Wo1, const float* __restrict__ bo1,
    float* __restrict__ out)
{
    __shared__ float xr[16][68];
    __shared__ float hid[16][36];
    const int tid = threadIdx.x;
    const int row0 = blockIdx.x * 16;
    {
        int r = tid >> 4, q = tid & 15;
        size_t off = (size_t)(row0 + r) * 64 + 4 * q;
        float s0 = 0.f, s1 = 0.f, s2 = 0.f, s3 = 0.f;
        #pragma unroll
        for (int s = 0; s < S; ++s) {
            ushort4 t = *reinterpret_cast<const ushort4*>(
                y + (size_t)s * N * 64 + off);
            s0 += bf2f(t.x); s1 += bf2f(t.y);
            s2 += bf2f(t.z); s3 += bf2f(t.w);
        }
        xr[r][4 * q + 0] = fmaxf(s0, 0.f);
        xr[r][4 * q + 1] = fmaxf(s1, 0.f);
        xr[r][4 * q + 2] = fmaxf(s2, 0.f);
        xr[r][4 * q + 3] = fmaxf(s3, 0.f);
    }
    __syncthreads();
    {
        int j = tid & 31, r0 = tid >> 5;
        #pragma unroll
        for (int rr = r0; rr < 16; rr += 8) {
            float a = bo0[j];
            #pragma unroll
            for (int k = 0; k < 64; ++k) a += xr[rr][k] * Wo0[k * 32 + j];
            hid[rr][j] = fmaxf(a, 0.f);
        }
    }
    __syncthreads();
    if (tid < 160) {
        int r = tid / 10, c = tid % 10;
        float a = bo1[c];
        #pragma unroll
        for (int k = 0; k < 32; ++k) a += hid[r][k] * Wo1[k * 10 + c];
        out[(size_t)(row0 + r) * 10 + c] = a;
    }
}

extern "C" void kernel_launch(void* const* d_in, const int* in_sizes, int n_in,
                              void* d_out, int out_size, void* d_ws, size_t ws_size,
                              hipStream_t stream) {
    const float* x   = (const float*)d_in[0];
    const float* adj = (const float*)d_in[1];
    const float* W0  = (const float*)d_in[2];
    const float* b0  = (const float*)d_in[3];
    const float* W1  = (const float*)d_in[4];
    const float* b1  = (const float*)d_in[5];
    const float* W2  = (const float*)d_in[6];
    const float* b2  = (const float*)d_in[7];
    const float* Wo0 = (const float*)d_in[8];
    const float* bo0 = (const float*)d_in[9];
    const float* Wo1 = (const float*)d_in[10];
    const float* bo1 = (const float*)d_in[11];
    float* out = (float*)d_out;

    char* ws = (char*)d_ws;
    constexpr int S1 = 16;                   // k-splits agg1 (klen = 512)
    constexpr int S2 = 8;                    // k-splits agg2/3 (klen = 1024)
    unsigned short* y_part = (unsigned short*)ws;                 // <= 8 MiB
    unsigned short* hT     = (unsigned short*)(ws + (16u << 20)); // 1 MiB
    unsigned char* adj_b   = (unsigned char*)(ws + (18u << 20));  // 64 MiB fp8
    const size_t NEED_FULL = ((size_t)18 << 20) + (size_t)N * N;
    const bool cache = ws_size >= NEED_FULL;

    lin0_kernel<<<128, 256, 0, stream>>>(x, W0, b0, hT);

    if (cache)
        agg_kernel<16, 64, 1><<<dim3(128, S1), 256, 0, stream>>>(adj, nullptr, adj_b, hT, y_part, N / S1);
    else
        agg_kernel<16, 64, 0><<<dim3(128, S1), 256, 0, stream>>>(adj, nullptr, nullptr, hT, y_part, N / S1);

    mid_linear_kernel<16, 32, S1><<<128, 256, 0, stream>>>(y_part, W1, b1, hT);

    if (cache)
        agg_kernel<32, 64, 2><<<dim3(128, S2), 256, 0, stream>>>(nullptr, adj_b, nullptr, hT, y_part, N / S2);
    else
        agg_kernel<32, 64, 0><<<dim3(128, S2), 256, 0, stream>>>(adj, nullptr, nullptr, hT, y_part, N / S2);

    mid_linear_kernel<32, 64, S2><<<128, 256, 0, stream>>>(y_part, W2, b2, hT);

    if (cache)
        agg_kernel<64, 64, 2><<<dim3(128, S2), 256, 0, stream>>>(nullptr, adj_b, nullptr, hT, y_part, N / S2);
    else
        agg_kernel<64, 64, 0><<<dim3(128, S2), 256, 0, stream>>>(adj, nullptr, nullptr, hT, y_part, N / S2);

    head_kernel<S2><<<512, 256, 0, stream>>>(y_part, Wo0, bo0, Wo1, bo1, out);
}

// Round 9
// 132.585 us; speedup vs baseline: 1.0749x; 1.0749x over previous
//
#include <hip/hip_runtime.h>

#define N 8192

typedef __attribute__((ext_vector_type(8))) short short8;
typedef __attribute__((ext_vector_type(4))) float f32x4;
typedef __attribute__((ext_vector_type(2))) float f32x2;

#define ADJ_SC 4096.0f
#define ADJ_ISC (1.0f / 4096.0f)

__device__ __forceinline__ unsigned short f2bf(float f) {
    union { float f; unsigned int u; } v; v.f = f;
    unsigned int r = v.u + 0x7FFFu + ((v.u >> 16) & 1u);  // round-to-nearest-even
    return (unsigned short)(r >> 16);
}

__device__ __forceinline__ float bf2f(unsigned short u) {
    return __builtin_bit_cast(float, (unsigned int)u << 16);
}

__device__ __forceinline__ void gl2lds16(const void* g, void* l) {
    __builtin_amdgcn_global_load_lds(
        (const __attribute__((address_space(1))) unsigned int*)g,
        (__attribute__((address_space(3))) unsigned int*)l, 16, 0, 0);
}

// 8 fp8-e4m3 bytes -> 8 bf16 (lossless: every e4m3 value is exactly a bf16)
__device__ __forceinline__ short8 fp8x8_to_bf16x8(uint2 a8) {
    short8 r;
    #pragma unroll
    for (int d = 0; d < 2; ++d) {
        unsigned int src = (d == 0) ? a8.x : a8.y;
        f32x2 lo = __builtin_amdgcn_cvt_pk_f32_fp8(src, false);
        f32x2 hi = __builtin_amdgcn_cvt_pk_f32_fp8(src, true);
        r[4 * d + 0] = (short)(__builtin_bit_cast(unsigned int, lo[0]) >> 16);
        r[4 * d + 1] = (short)(__builtin_bit_cast(unsigned int, lo[1]) >> 16);
        r[4 * d + 2] = (short)(__builtin_bit_cast(unsigned int, hi[0]) >> 16);
        r[4 * d + 3] = (short)(__builtin_bit_cast(unsigned int, hi[1]) >> 16);
    }
    return r;
}

#define BAR_SCHED() do { __builtin_amdgcn_s_barrier(); \
                         __builtin_amdgcn_sched_barrier(0); } while (0)

// ---------------------------------------------------------------------------
// Aggregation: y_part[ks] = adj[rows, kslice] @ h   (partials stored bf16)
// MODE 0: adj f32 (no writeback)     [BK=128, counted-vmcnt reg prefetch]
// MODE 1: adj f32 + pre-swizzled fp8-e4m3 writeback (adj*4096)  [BK=128]
// MODE 2: linear gl2lds of pre-swizzled fp8 adj (BK=64), double-buffered,
//   lossless fp8->bf16 expand in regs, bf16 MFMA, acc *= 2^-12 at epilogue.
// hT stored PRE-SWIZZLED (elem ^ ((c&7)<<3)); adj_b pre-swizzled within
// 64-B k-chunks (byte ^ ((row&7)<<3)). LDS fragment reads apply same XOR.
// BM=64 rows, 4 waves, wave w -> rows [16w,16w+16).
// ---------------------------------------------------------------------------
template<int NC, int BK, int MODE>
__global__ __launch_bounds__(256) void agg_kernel(
    const float* __restrict__ adj,
    const unsigned char* __restrict__ adj_b_in,
    unsigned char* __restrict__ adj_b_out,
    const unsigned short* __restrict__ hT,   // [NC][N] bf16, pre-swizzled
    unsigned short* __restrict__ y,          // [S][N][NC] bf16 partials
    int klen)
{
    constexpr int BM = 64;
    constexpr int NCT = NC / 16;

    const int tid = threadIdx.x;
    const int w  = tid >> 6;
    const int l  = tid & 63;
    const int hi = l >> 4;
    const int lr = l & 15;
    const int row0 = blockIdx.x * BM;
    const int k00  = blockIdx.y * klen;
    const int nt   = klen / BK;

    f32x4 acc[NCT];
    #pragma unroll
    for (int i = 0; i < NCT; ++i) acc[i] = f32x4{0.f, 0.f, 0.f, 0.f};

    if constexpr (MODE == 2) {
        // fp8 adj tile: BK bytes/row; bf16 hT tile: 2*BK bytes/row
        __shared__ unsigned char as2_[2][BM * BK];
        __shared__ unsigned short hs2_[2][NC * BK];
        constexpr int TA = (BM * BK) / 1024;       // 1KB chunks, adj tile
        constexpr int TH = (NC * 2 * BK) / 1024;   // 1KB chunks, hT tile
        constexpr int GRA = BK / 16, RPA = 1024 / BK;
        constexpr int GRH = (2 * BK) / 16, RPH = 1024 / (2 * BK);
        constexpr int KW = (TA + TH) / 4;          // per-wave gl2lds per stage

        auto stage = [&](char* ab, char* hb, int t) {
            const int kb = k00 + t * BK;
            #pragma unroll
            for (int i = w; i < TA; i += 4) {
                int r = i * RPA + l / GRA, g = l % GRA;
                gl2lds16(adj_b_in + (size_t)(row0 + r) * N + kb + 16 * g,
                         ab + i * 1024);
            }
            #pragma unroll
            for (int i = w; i < TH; i += 4) {
                int c = i * RPH + l / GRH, g = l % GRH;
                gl2lds16(hT + (size_t)c * N + kb + 8 * g, hb + i * 1024);
            }
        };

        stage((char*)as2_[0], (char*)hs2_[0], 0);
        for (int t = 0; t < nt; ++t) {
            char* ca = (char*)as2_[t & 1];
            char* ch = (char*)hs2_[t & 1];
            char* na = (char*)as2_[(t & 1) ^ 1];
            char* nh = (char*)hs2_[(t & 1) ^ 1];
            if (t + 1 < nt) {
                stage(na, nh, t + 1);
                asm volatile("s_waitcnt vmcnt(%0)" :: "n"(KW) : "memory");
            } else {
                asm volatile("s_waitcnt vmcnt(0)" ::: "memory");
            }
            BAR_SCHED();
            #pragma unroll
            for (int kk = 0; kk < BK; kk += 32) {
                const int arow = 16 * w + lr;
                uint2 a8 = *reinterpret_cast<const uint2*>(
                    ca + arow * BK + ((kk + 8 * hi) ^ ((arow & 7) << 3)));
                short8 a = fp8x8_to_bf16x8(a8);
                #pragma unroll
                for (int ct = 0; ct < NCT; ++ct) {
                    const int bcol = 16 * ct + lr;
                    short8 b = *reinterpret_cast<const short8*>(
                        ch + bcol * (2 * BK) + ((2 * kk + 16 * hi) ^ ((bcol & 7) << 4)));
                    acc[ct] = __builtin_amdgcn_mfma_f32_16x16x32_bf16(a, b, acc[ct], 0, 0, 0);
                }
            }
            asm volatile("s_waitcnt lgkmcnt(0)" ::: "memory");
            BAR_SCHED();
        }
        #pragma unroll
        for (int ct = 0; ct < NCT; ++ct)
            #pragma unroll
            for (int r = 0; r < 4; ++r) acc[ct][r] *= ADJ_ISC;
    } else {
        // MODE 0/1: BK==128. Counted-vmcnt reg-prefetch pipeline (R7-proven).
        __shared__ unsigned short as_[BM * BK];
        __shared__ unsigned short hs_[NC * BK];
        char* asb = (char*)as_;
        char* hsb = (char*)hs_;
        constexpr int ROWB = BK * 2;
        constexpr int LV = 8;
        constexpr int TH = (NC * ROWB) / 1024;
        float4 pf[LV];
        #pragma unroll
        for (int it = 0; it < LV; ++it) {
            int idx = tid + it * 256, r = idx >> 5, q = idx & 31;
            const f32x4* p = reinterpret_cast<const f32x4*>(
                adj + (size_t)(row0 + r) * N + k00 + 4 * q);
            f32x4 t0 = __builtin_nontemporal_load(p);
            pf[it] = float4{t0[0], t0[1], t0[2], t0[3]};
        }
        for (int t = 0; t < nt; ++t) {
            const int kb = k00 + t * BK;
            // (1) hT tile: linear gl2lds (content pre-swizzled)  [oldest]
            #pragma unroll
            for (int i = w; i < TH; i += 4) {
                int c = i * 4 + l / 16;   // 4 rows per 1KB chunk (ROWB=256)
                int g = l % 16;
                gl2lds16(hT + (size_t)c * N + kb + 8 * g, hsb + i * 1024);
            }
            __builtin_amdgcn_sched_barrier(0);
            // (2) convert + fp8 writeback store + swizzled bf16 LDS write
            #pragma unroll
            for (int it = 0; it < LV; ++it) {
                int idx = tid + it * 256, r = idx >> 5, q = idx & 31;
                ushort4 u;
                u.x = f2bf(pf[it].x); u.y = f2bf(pf[it].y);
                u.z = f2bf(pf[it].z); u.w = f2bf(pf[it].w);
                if (MODE == 1) {
                    unsigned int pk = 0;
                    pk = __builtin_amdgcn_cvt_pk_fp8_f32(
                        pf[it].x * ADJ_SC, pf[it].y * ADJ_SC, pk, false);
                    pk = __builtin_amdgcn_cvt_pk_fp8_f32(
                        pf[it].z * ADJ_SC, pf[it].w * ADJ_SC, pk, true);
                    *reinterpret_cast<unsigned int*>(
                        adj_b_out + (size_t)(row0 + r) * N + kb +
                        ((4 * q) ^ ((r & 7) << 3))) = pk;
                }
                *reinterpret_cast<ushort4*>(
                    asb + r * ROWB + ((8 * q) ^ ((r & 7) << 4))) = u;
            }
            __builtin_amdgcn_sched_barrier(0);
            // (3) next-tile prefetch [newest, stays in flight across barriers]
            if (t + 1 < nt) {
                #pragma unroll
                for (int it = 0; it < LV; ++it) {
                    int idx = tid + it * 256, r = idx >> 5, q = idx & 31;
                    const f32x4* p = reinterpret_cast<const f32x4*>(
                        adj + (size_t)(row0 + r) * N + kb + BK + 4 * q);
                    f32x4 t0 = __builtin_nontemporal_load(p);
                    pf[it] = float4{t0[0], t0[1], t0[2], t0[3]};
                }
                __builtin_amdgcn_sched_barrier(0);
                if (MODE == 1)
                    asm volatile("s_waitcnt vmcnt(16) lgkmcnt(0)" ::: "memory");
                else
                    asm volatile("s_waitcnt vmcnt(8) lgkmcnt(0)" ::: "memory");
            } else {
                if (MODE == 1)
                    asm volatile("s_waitcnt vmcnt(8) lgkmcnt(0)" ::: "memory");
                else
                    asm volatile("s_waitcnt vmcnt(0) lgkmcnt(0)" ::: "memory");
            }
            BAR_SCHED();
            // (4) MFMA phase
            #pragma unroll
            for (int kk = 0; kk < BK; kk += 32) {
                const int arow = 16 * w + lr;
                short8 a = *reinterpret_cast<const short8*>(
                    asb + arow * ROWB + ((2 * kk + 16 * hi) ^ ((arow & 7) << 4)));
                #pragma unroll
                for (int ct = 0; ct < NCT; ++ct) {
                    const int bcol = 16 * ct + lr;
                    short8 b = *reinterpret_cast<const short8*>(
                        hsb + bcol * ROWB + ((2 * kk + 16 * hi) ^ ((bcol & 7) << 4)));
                    acc[ct] = __builtin_amdgcn_mfma_f32_16x16x32_bf16(a, b, acc[ct], 0, 0, 0);
                }
            }
            asm volatile("s_waitcnt lgkmcnt(0)" ::: "memory");
            BAR_SCHED();
        }
    }
    // write bf16 partials: D layout col=lane&15, row=4*(lane>>4)+reg
    unsigned short* yp = y + (size_t)blockIdx.y * N * NC;
    #pragma unroll
    for (int ct = 0; ct < NCT; ++ct) {
        #pragma unroll
        for (int r = 0; r < 4; ++r) {
            yp[(size_t)(row0 + 16 * w + 4 * hi + r) * NC + 16 * ct + lr] =
                f2bf(acc[ct][r]);
        }
    }
}

// ---------------------------------------------------------------------------
// lin0: hT = bf16((x @ W0 + b0)^T), pre-swizzled columns
// ---------------------------------------------------------------------------
__global__ __launch_bounds__(256) void lin0_kernel(
    const float* __restrict__ x, const float* __restrict__ W,
    const float* __restrict__ b, unsigned short* __restrict__ hT)
{
    __shared__ float xs[64][129];
    const int tid = threadIdx.x;
    const int row0 = blockIdx.x * 64;
    #pragma unroll
    for (int it = 0; it < 8; ++it) {
        int idx = tid + it * 256;
        int r = idx >> 5, q = idx & 31;
        float4 v = *reinterpret_cast<const float4*>(x + (size_t)(row0 + r) * 128 + 4 * q);
        xs[r][4 * q + 0] = v.x; xs[r][4 * q + 1] = v.y;
        xs[r][4 * q + 2] = v.z; xs[r][4 * q + 3] = v.w;
    }
    __syncthreads();
    const int w = tid >> 6, l = tid & 63;
    float acc[4] = {b[w], b[w + 4], b[w + 8], b[w + 12]};
    for (int k = 0; k < 128; ++k) {
        float xv = xs[l][k];
        #pragma unroll
        for (int cc = 0; cc < 4; ++cc) acc[cc] += xv * W[k * 16 + w + 4 * cc];
    }
    #pragma unroll
    for (int cc = 0; cc < 4; ++cc) {
        int c = w + 4 * cc;
        hT[(size_t)c * N + ((row0 + l) ^ ((c & 7) << 3))] = f2bf(acc[cc]);
    }
}

// ---------------------------------------------------------------------------
// mid linear: hT = bf16((relu(sum_s y_s) @ W + b)^T), pre-swizzled columns
// y input is bf16 partials.
// ---------------------------------------------------------------------------
template<int NIN, int NOUT, int S>
__global__ __launch_bounds__(256) void mid_linear_kernel(
    const unsigned short* __restrict__ y,  // [S][N][NIN] bf16
    const float* __restrict__ W,           // [NIN][NOUT]
    const float* __restrict__ b,
    unsigned short* __restrict__ hT)       // [NOUT][N]
{
    __shared__ float xs[64][NIN + 1];
    const int tid = threadIdx.x;
    const int row0 = blockIdx.x * 64;
    constexpr int NF4 = 64 * NIN / 4;
    #pragma unroll
    for (int idx0 = 0; idx0 < NF4; idx0 += 256) {
        int idx = idx0 + tid;
        if (NF4 >= 256 || idx < NF4) {
            int r = idx / (NIN / 4), q = idx % (NIN / 4);
            size_t off = (size_t)(row0 + r) * NIN + 4 * q;
            float s0 = 0.f, s1 = 0.f, s2 = 0.f, s3 = 0.f;
            #pragma unroll
            for (int s = 0; s < S; ++s) {
                ushort4 t = *reinterpret_cast<const ushort4*>(
                    y + (size_t)s * N * NIN + off);
                s0 += bf2f(t.x); s1 += bf2f(t.y);
                s2 += bf2f(t.z); s3 += bf2f(t.w);
            }
            xs[r][4 * q + 0] = fmaxf(s0, 0.f);
            xs[r][4 * q + 1] = fmaxf(s1, 0.f);
            xs[r][4 * q + 2] = fmaxf(s2, 0.f);
            xs[r][4 * q + 3] = fmaxf(s3, 0.f);
        }
    }
    __syncthreads();
    const int w = tid >> 6, l = tid & 63;
    constexpr int CC = NOUT / 4;
    float acc[CC];
    #pragma unroll
    for (int cc = 0; cc < CC; ++cc) acc[cc] = b[w + 4 * cc];
    for (int k = 0; k < NIN; ++k) {
        float xv = xs[l][k];
        #pragma unroll
        for (int cc = 0; cc < CC; ++cc) acc[cc] += xv * W[k * NOUT + w + 4 * cc];
    }
    #pragma unroll
    for (int cc = 0; cc < CC; ++cc) {
        int c = w + 4 * cc;
        hT[(size_t)c * N + ((row0 + l) ^ ((c & 7) << 3))] = f2bf(acc[cc]);
    }
}

// ---------------------------------------------------------------------------
// head: out = relu(relu(sum_s y_s) @ Wo0 + bo0) @ Wo1 + bo1, 16 rows/block
// y input bf16.
// ---------------------------------------------------------------------------
template<int S>
__global__ __launch_bounds__(256) void head_kernel(
    const unsigned short* __restrict__ y,  // [S][N][64] bf16
    const float* __restrict__ Wo0, const float* __restrict__ bo0,
    const float* __restrict__ Wo1, const float* __restrict__ bo1,
    float* __restrict__ out)
{
    __shared__ float xr[16][68];
    __shared__ float hid[16][36];
    const int tid = threadIdx.x;
    const int row0 = blockIdx.x * 16;
    {
        int r = tid >> 4, q = tid & 15;
        size_t off = (size_t)(row0 + r) * 64 + 4 * q;
        float s0 = 0.f, s1 = 0.f, s2 = 0.f, s3 = 0.f;
        #pragma unroll
        for (int s = 0; s < S; ++s) {
            ushort4 t = *reinterpret_cast<const ushort4*>(
                y + (size_t)s * N * 64 + off);
            s0 += bf2f(t.x); s1 += bf2f(t.y);
            s2 += bf2f(t.z); s3 += bf2f(t.w);
        }
        xr[r][4 * q + 0] = fmaxf(s0, 0.f);
        xr[r][4 * q + 1] = fmaxf(s1, 0.f);
        xr[r][4 * q + 2] = fmaxf(s2, 0.f);
        xr[r][4 * q + 3] = fmaxf(s3, 0.f);
    }
    __syncthreads();
    {
        int j = tid & 31, r0 = tid >> 5;
        #pragma unroll
        for (int rr = r0; rr < 16; rr += 8) {
            float a = bo0[j];
            #pragma unroll
            for (int k = 0; k < 64; ++k) a += xr[rr][k] * Wo0[k * 32 + j];
            hid[rr][j] = fmaxf(a, 0.f);
        }
    }
    __syncthreads();
    if (tid < 160) {
        int r = tid / 10, c = tid % 10;
        float a = bo1[c];
        #pragma unroll
        for (int k = 0; k < 32; ++k) a += hid[r][k] * Wo1[k * 10 + c];
        out[(size_t)(row0 + r) * 10 + c] = a;
    }
}

extern "C" void kernel_launch(void* const* d_in, const int* in_sizes, int n_in,
                              void* d_out, int out_size, void* d_ws, size_t ws_size,
                              hipStream_t stream) {
    const float* x   = (const float*)d_in[0];
    const float* adj = (const float*)d_in[1];
    const float* W0  = (const float*)d_in[2];
    const float* b0  = (const float*)d_in[3];
    const float* W1  = (const float*)d_in[4];
    const float* b1  = (const float*)d_in[5];
    const float* W2  = (const float*)d_in[6];
    const float* b2  = (const float*)d_in[7];
    const float* Wo0 = (const float*)d_in[8];
    const float* bo0 = (const float*)d_in[9];
    const float* Wo1 = (const float*)d_in[10];
    const float* bo1 = (const float*)d_in[11];
    float* out = (float*)d_out;

    char* ws = (char*)d_ws;
    constexpr int S = 16;                    // k-splits (klen = 512)
    constexpr int KLEN = N / S;
    unsigned short* y_part = (unsigned short*)ws;                 // <= 16 MiB
    unsigned short* hT     = (unsigned short*)(ws + (16u << 20)); // 1 MiB
    unsigned char* adj_b   = (unsigned char*)(ws + (18u << 20));  // 64 MiB fp8
    const size_t NEED_FULL = ((size_t)18 << 20) + (size_t)N * N;
    const bool cache = ws_size >= NEED_FULL;

    lin0_kernel<<<128, 256, 0, stream>>>(x, W0, b0, hT);

    if (cache)
        agg_kernel<16, 128, 1><<<dim3(128, S), 256, 0, stream>>>(adj, nullptr, adj_b, hT, y_part, KLEN);
    else
        agg_kernel<16, 128, 0><<<dim3(128, S), 256, 0, stream>>>(adj, nullptr, nullptr, hT, y_part, KLEN);

    mid_linear_kernel<16, 32, S><<<128, 256, 0, stream>>>(y_part, W1, b1, hT);

    if (cache)
        agg_kernel<32, 64, 2><<<dim3(128, S), 256, 0, stream>>>(nullptr, adj_b, nullptr, hT, y_part, KLEN);
    else
        agg_kernel<32, 64, 0><<<dim3(128, S), 256, 0, stream>>>(adj, nullptr, nullptr, hT, y_part, KLEN);

    mid_linear_kernel<32, 64, S><<<128, 256, 0, stream>>>(y_part, W2, b2, hT);

    if (cache)
        agg_kernel<64, 64, 2><<<dim3(128, S), 256, 0, stream>>>(nullptr, adj_b, nullptr, hT, y_part, KLEN);
    else
        agg_kernel<64, 64, 0><<<dim3(128, S), 256, 0, stream>>>(adj, nullptr, nullptr, hT, y_part, KLEN);

    head_kernel<S><<<512, 256, 0, stream>>>(y_part, Wo0, bo0, Wo1, bo1, out);
}

// Round 10
// 130.950 us; speedup vs baseline: 1.0883x; 1.0125x over previous
//
#include <hip/hip_runtime.h>

#define N 8192

typedef __attribute__((ext_vector_type(8))) short short8;
typedef __attribute__((ext_vector_type(4))) float f32x4;
typedef __attribute__((ext_vector_type(2))) float f32x2;

#define ADJ_SC 4096.0f
#define ADJ_ISC (1.0f / 4096.0f)

__device__ __forceinline__ unsigned short f2bf(float f) {
    union { float f; unsigned int u; } v; v.f = f;
    unsigned int r = v.u + 0x7FFFu + ((v.u >> 16) & 1u);  // round-to-nearest-even
    return (unsigned short)(r >> 16);
}

__device__ __forceinline__ float bf2f(unsigned short u) {
    return __builtin_bit_cast(float, (unsigned int)u << 16);
}

__device__ __forceinline__ void gl2lds16(const void* g, void* l) {
    __builtin_amdgcn_global_load_lds(
        (const __attribute__((address_space(1))) unsigned int*)g,
        (__attribute__((address_space(3))) unsigned int*)l, 16, 0, 0);
}

// 8 fp8-e4m3 bytes -> 8 bf16 (lossless: every e4m3 value is exactly a bf16)
__device__ __forceinline__ short8 fp8x8_to_bf16x8(uint2 a8) {
    short8 r;
    #pragma unroll
    for (int d = 0; d < 2; ++d) {
        unsigned int src = (d == 0) ? a8.x : a8.y;
        f32x2 lo = __builtin_amdgcn_cvt_pk_f32_fp8(src, false);
        f32x2 hi = __builtin_amdgcn_cvt_pk_f32_fp8(src, true);
        r[4 * d + 0] = (short)(__builtin_bit_cast(unsigned int, lo[0]) >> 16);
        r[4 * d + 1] = (short)(__builtin_bit_cast(unsigned int, lo[1]) >> 16);
        r[4 * d + 2] = (short)(__builtin_bit_cast(unsigned int, hi[0]) >> 16);
        r[4 * d + 3] = (short)(__builtin_bit_cast(unsigned int, hi[1]) >> 16);
    }
    return r;
}

#define BAR_SCHED() do { __builtin_amdgcn_s_barrier(); \
                         __builtin_amdgcn_sched_barrier(0); } while (0)

// ---------------------------------------------------------------------------
// Aggregation: y_part[ks] = adj[rows, kslice] @ h   (partials stored bf16)
// MODE 0: adj f32 (no writeback)     [BK=128, counted-vmcnt reg prefetch]
// MODE 1: adj f32 + pre-swizzled fp8-e4m3 writeback (adj*4096)  [BK=128]
// MODE 2: linear gl2lds of pre-swizzled fp8 adj (BK=64), double-buffered,
//   lossless fp8->bf16 expand in regs, bf16 MFMA, acc *= 2^-12 at epilogue.
// hT stored PRE-SWIZZLED (elem ^ ((c&7)<<3)); adj_b pre-swizzled within
// 64-B k-chunks (byte ^ ((row&7)<<3)). LDS fragment reads apply same XOR.
// BM=64 rows, 4 waves, wave w -> rows [16w,16w+16).   (verbatim R9)
// ---------------------------------------------------------------------------
template<int NC, int BK, int MODE>
__global__ __launch_bounds__(256) void agg_kernel(
    const float* __restrict__ adj,
    const unsigned char* __restrict__ adj_b_in,
    unsigned char* __restrict__ adj_b_out,
    const unsigned short* __restrict__ hT,   // [NC][N] bf16, pre-swizzled
    unsigned short* __restrict__ y,          // [S][N][NC] bf16 partials
    int klen)
{
    constexpr int BM = 64;
    constexpr int NCT = NC / 16;

    const int tid = threadIdx.x;
    const int w  = tid >> 6;
    const int l  = tid & 63;
    const int hi = l >> 4;
    const int lr = l & 15;
    const int row0 = blockIdx.x * BM;
    const int k00  = blockIdx.y * klen;
    const int nt   = klen / BK;

    f32x4 acc[NCT];
    #pragma unroll
    for (int i = 0; i < NCT; ++i) acc[i] = f32x4{0.f, 0.f, 0.f, 0.f};

    if constexpr (MODE == 2) {
        // fp8 adj tile: BK bytes/row; bf16 hT tile: 2*BK bytes/row
        __shared__ unsigned char as2_[2][BM * BK];
        __shared__ unsigned short hs2_[2][NC * BK];
        constexpr int TA = (BM * BK) / 1024;       // 1KB chunks, adj tile
        constexpr int TH = (NC * 2 * BK) / 1024;   // 1KB chunks, hT tile
        constexpr int GRA = BK / 16, RPA = 1024 / BK;
        constexpr int GRH = (2 * BK) / 16, RPH = 1024 / (2 * BK);
        constexpr int KW = (TA + TH) / 4;          // per-wave gl2lds per stage

        auto stage = [&](char* ab, char* hb, int t) {
            const int kb = k00 + t * BK;
            #pragma unroll
            for (int i = w; i < TA; i += 4) {
                int r = i * RPA + l / GRA, g = l % GRA;
                gl2lds16(adj_b_in + (size_t)(row0 + r) * N + kb + 16 * g,
                         ab + i * 1024);
            }
            #pragma unroll
            for (int i = w; i < TH; i += 4) {
                int c = i * RPH + l / GRH, g = l % GRH;
                gl2lds16(hT + (size_t)c * N + kb + 8 * g, hb + i * 1024);
            }
        };

        stage((char*)as2_[0], (char*)hs2_[0], 0);
        for (int t = 0; t < nt; ++t) {
            char* ca = (char*)as2_[t & 1];
            char* ch = (char*)hs2_[t & 1];
            char* na = (char*)as2_[(t & 1) ^ 1];
            char* nh = (char*)hs2_[(t & 1) ^ 1];
            if (t + 1 < nt) {
                stage(na, nh, t + 1);
                asm volatile("s_waitcnt vmcnt(%0)" :: "n"(KW) : "memory");
            } else {
                asm volatile("s_waitcnt vmcnt(0)" ::: "memory");
            }
            BAR_SCHED();
            #pragma unroll
            for (int kk = 0; kk < BK; kk += 32) {
                const int arow = 16 * w + lr;
                uint2 a8 = *reinterpret_cast<const uint2*>(
                    ca + arow * BK + ((kk + 8 * hi) ^ ((arow & 7) << 3)));
                short8 a = fp8x8_to_bf16x8(a8);
                #pragma unroll
                for (int ct = 0; ct < NCT; ++ct) {
                    const int bcol = 16 * ct + lr;
                    short8 b = *reinterpret_cast<const short8*>(
                        ch + bcol * (2 * BK) + ((2 * kk + 16 * hi) ^ ((bcol & 7) << 4)));
                    acc[ct] = __builtin_amdgcn_mfma_f32_16x16x32_bf16(a, b, acc[ct], 0, 0, 0);
                }
            }
            asm volatile("s_waitcnt lgkmcnt(0)" ::: "memory");
            BAR_SCHED();
        }
        #pragma unroll
        for (int ct = 0; ct < NCT; ++ct)
            #pragma unroll
            for (int r = 0; r < 4; ++r) acc[ct][r] *= ADJ_ISC;
    } else {
        // MODE 0/1: BK==128. Counted-vmcnt reg-prefetch pipeline (R7-proven).
        __shared__ unsigned short as_[BM * BK];
        __shared__ unsigned short hs_[NC * BK];
        char* asb = (char*)as_;
        char* hsb = (char*)hs_;
        constexpr int ROWB = BK * 2;
        constexpr int LV = 8;
        constexpr int TH = (NC * ROWB) / 1024;
        float4 pf[LV];
        #pragma unroll
        for (int it = 0; it < LV; ++it) {
            int idx = tid + it * 256, r = idx >> 5, q = idx & 31;
            const f32x4* p = reinterpret_cast<const f32x4*>(
                adj + (size_t)(row0 + r) * N + k00 + 4 * q);
            f32x4 t0 = __builtin_nontemporal_load(p);
            pf[it] = float4{t0[0], t0[1], t0[2], t0[3]};
        }
        for (int t = 0; t < nt; ++t) {
            const int kb = k00 + t * BK;
            // (1) hT tile: linear gl2lds (content pre-swizzled)  [oldest]
            #pragma unroll
            for (int i = w; i < TH; i += 4) {
                int c = i * 4 + l / 16;   // 4 rows per 1KB chunk (ROWB=256)
                int g = l % 16;
                gl2lds16(hT + (size_t)c * N + kb + 8 * g, hsb + i * 1024);
            }
            __builtin_amdgcn_sched_barrier(0);
            // (2) convert + fp8 writeback store + swizzled bf16 LDS write
            #pragma unroll
            for (int it = 0; it < LV; ++it) {
                int idx = tid + it * 256, r = idx >> 5, q = idx & 31;
                ushort4 u;
                u.x = f2bf(pf[it].x); u.y = f2bf(pf[it].y);
                u.z = f2bf(pf[it].z); u.w = f2bf(pf[it].w);
                if (MODE == 1) {
                    unsigned int pk = 0;
                    pk = __builtin_amdgcn_cvt_pk_fp8_f32(
                        pf[it].x * ADJ_SC, pf[it].y * ADJ_SC, pk, false);
                    pk = __builtin_amdgcn_cvt_pk_fp8_f32(
                        pf[it].z * ADJ_SC, pf[it].w * ADJ_SC, pk, true);
                    *reinterpret_cast<unsigned int*>(
                        adj_b_out + (size_t)(row0 + r) * N + kb +
                        ((4 * q) ^ ((r & 7) << 3))) = pk;
                }
                *reinterpret_cast<ushort4*>(
                    asb + r * ROWB + ((8 * q) ^ ((r & 7) << 4))) = u;
            }
            __builtin_amdgcn_sched_barrier(0);
            // (3) next-tile prefetch [newest, stays in flight across barriers]
            if (t + 1 < nt) {
                #pragma unroll
                for (int it = 0; it < LV; ++it) {
                    int idx = tid + it * 256, r = idx >> 5, q = idx & 31;
                    const f32x4* p = reinterpret_cast<const f32x4*>(
                        adj + (size_t)(row0 + r) * N + kb + BK + 4 * q);
                    f32x4 t0 = __builtin_nontemporal_load(p);
                    pf[it] = float4{t0[0], t0[1], t0[2], t0[3]};
                }
                __builtin_amdgcn_sched_barrier(0);
                if (MODE == 1)
                    asm volatile("s_waitcnt vmcnt(16) lgkmcnt(0)" ::: "memory");
                else
                    asm volatile("s_waitcnt vmcnt(8) lgkmcnt(0)" ::: "memory");
            } else {
                if (MODE == 1)
                    asm volatile("s_waitcnt vmcnt(8) lgkmcnt(0)" ::: "memory");
                else
                    asm volatile("s_waitcnt vmcnt(0) lgkmcnt(0)" ::: "memory");
            }
            BAR_SCHED();
            // (4) MFMA phase
            #pragma unroll
            for (int kk = 0; kk < BK; kk += 32) {
                const int arow = 16 * w + lr;
                short8 a = *reinterpret_cast<const short8*>(
                    asb + arow * ROWB + ((2 * kk + 16 * hi) ^ ((arow & 7) << 4)));
                #pragma unroll
                for (int ct = 0; ct < NCT; ++ct) {
                    const int bcol = 16 * ct + lr;
                    short8 b = *reinterpret_cast<const short8*>(
                        hsb + bcol * ROWB + ((2 * kk + 16 * hi) ^ ((bcol & 7) << 4)));
                    acc[ct] = __builtin_amdgcn_mfma_f32_16x16x32_bf16(a, b, acc[ct], 0, 0, 0);
                }
            }
            asm volatile("s_waitcnt lgkmcnt(0)" ::: "memory");
            BAR_SCHED();
        }
    }
    // write bf16 partials: D layout col=lane&15, row=4*(lane>>4)+reg
    unsigned short* yp = y + (size_t)blockIdx.y * N * NC;
    #pragma unroll
    for (int ct = 0; ct < NCT; ++ct) {
        #pragma unroll
        for (int r = 0; r < 4; ++r) {
            yp[(size_t)(row0 + 16 * w + 4 * hi + r) * NC + 16 * ct + lr] =
                f2bf(acc[ct][r]);
        }
    }
}

// ---------------------------------------------------------------------------
// lin0: hT = bf16((x @ W0 + b0)^T), pre-swizzled columns.
// 16 rows/block -> 512 blocks (2/CU). thread -> (row=tid&15, col=tid>>4).
// ---------------------------------------------------------------------------
__global__ __launch_bounds__(256) void lin0_kernel(
    const float* __restrict__ x, const float* __restrict__ W,
    const float* __restrict__ b, unsigned short* __restrict__ hT)
{
    __shared__ float xs[16][129];
    const int tid = threadIdx.x;
    const int row0 = blockIdx.x * 16;
    #pragma unroll
    for (int it = 0; it < 2; ++it) {
        int idx = tid + it * 256;             // 0..511 = 16 rows x 32 float4
        int r = idx >> 5, q = idx & 31;
        float4 v = *reinterpret_cast<const float4*>(x + (size_t)(row0 + r) * 128 + 4 * q);
        xs[r][4 * q + 0] = v.x; xs[r][4 * q + 1] = v.y;
        xs[r][4 * q + 2] = v.z; xs[r][4 * q + 3] = v.w;
    }
    __syncthreads();
    const int r = tid & 15, c = tid >> 4;     // 16 rows x 16 cols
    float acc = b[c];
    #pragma unroll 4
    for (int k = 0; k < 128; ++k) acc += xs[r][k] * W[k * 16 + c];
    hT[(size_t)c * N + ((row0 + r) ^ ((c & 7) << 3))] = f2bf(acc);
}

// ---------------------------------------------------------------------------
// mid linear: hT = bf16((relu(sum_s y_s) @ W + b)^T), pre-swizzled columns.
// 16 rows/block -> 512 blocks. Same accumulation order as R9 (bit-identical).
// ---------------------------------------------------------------------------
template<int NIN, int NOUT, int S>
__global__ __launch_bounds__(256) void mid_linear_kernel(
    const unsigned short* __restrict__ y,  // [S][N][NIN] bf16
    const float* __restrict__ W,           // [NIN][NOUT]
    const float* __restrict__ b,
    unsigned short* __restrict__ hT)       // [NOUT][N]
{
    __shared__ float xs[16][NIN + 1];
    const int tid = threadIdx.x;
    const int row0 = blockIdx.x * 16;
    constexpr int NF4 = 16 * NIN / 4;      // 64 / 128 / 256
    if (tid < NF4) {
        int r = tid / (NIN / 4), q = tid % (NIN / 4);
        size_t off = (size_t)(row0 + r) * NIN + 4 * q;
        float s0 = 0.f, s1 = 0.f, s2 = 0.f, s3 = 0.f;
        #pragma unroll
        for (int s = 0; s < S; ++s) {
            ushort4 t = *reinterpret_cast<const ushort4*>(
                y + (size_t)s * N * NIN + off);
            s0 += bf2f(t.x); s1 += bf2f(t.y);
            s2 += bf2f(t.z); s3 += bf2f(t.w);
        }
        xs[r][4 * q + 0] = fmaxf(s0, 0.f);
        xs[r][4 * q + 1] = fmaxf(s1, 0.f);
        xs[r][4 * q + 2] = fmaxf(s2, 0.f);
        xs[r][4 * q + 3] = fmaxf(s3, 0.f);
    }
    __syncthreads();
    const int r = tid & 15, c0 = tid >> 4;   // 16 rows x 16 col-slots
    constexpr int CC = NOUT / 16;
    float acc[CC];
    #pragma unroll
    for (int cc = 0; cc < CC; ++cc) acc[cc] = b[c0 + 16 * cc];
    for (int k = 0; k < NIN; ++k) {
        float xv = xs[r][k];
        #pragma unroll
        for (int cc = 0; cc < CC; ++cc) acc[cc] += xv * W[k * NOUT + c0 + 16 * cc];
    }
    #pragma unroll
    for (int cc = 0; cc < CC; ++cc) {
        int c = c0 + 16 * cc;
        hT[(size_t)c * N + ((row0 + r) ^ ((c & 7) << 3))] = f2bf(acc[cc]);
    }
}

// ---------------------------------------------------------------------------
// head: out = relu(relu(sum_s y_s) @ Wo0 + bo0) @ Wo1 + bo1, 16 rows/block
// ---------------------------------------------------------------------------
template<int S>
__global__ __launch_bounds__(256) void head_kernel(
    const unsigned short* __restrict__ y,  // [S][N][64] bf16
    const float* __restrict__ Wo0, const float* __restrict__ bo0,
    const float* __restrict__ Wo1, const float* __restrict__ bo1,
    float* __restrict__ out)
{
    __shared__ float xr[16][68];
    __shared__ float hid[16][36];
    const int tid = threadIdx.x;
    const int row0 = blockIdx.x * 16;
    {
        int r = tid >> 4, q = tid & 15;
        size_t off = (size_t)(row0 + r) * 64 + 4 * q;
        float s0 = 0.f, s1 = 0.f, s2 = 0.f, s3 = 0.f;
        #pragma unroll
        for (int s = 0; s < S; ++s) {
            ushort4 t = *reinterpret_cast<const ushort4*>(
                y + (size_t)s * N * 64 + off);
            s0 += bf2f(t.x); s1 += bf2f(t.y);
            s2 += bf2f(t.z); s3 += bf2f(t.w);
        }
        xr[r][4 * q + 0] = fmaxf(s0, 0.f);
        xr[r][4 * q + 1] = fmaxf(s1, 0.f);
        xr[r][4 * q + 2] = fmaxf(s2, 0.f);
        xr[r][4 * q + 3] = fmaxf(s3, 0.f);
    }
    __syncthreads();
    {
        int j = tid & 31, r0 = tid >> 5;
        #pragma unroll
        for (int rr = r0; rr < 16; rr += 8) {
            float a = bo0[j];
            #pragma unroll
            for (int k = 0; k < 64; ++k) a += xr[rr][k] * Wo0[k * 32 + j];
            hid[rr][j] = fmaxf(a, 0.f);
        }
    }
    __syncthreads();
    if (tid < 160) {
        int r = tid / 10, c = tid % 10;
        float a = bo1[c];
        #pragma unroll
        for (int k = 0; k < 32; ++k) a += hid[r][k] * Wo1[k * 10 + c];
        out[(size_t)(row0 + r) * 10 + c] = a;
    }
}

extern "C" void kernel_launch(void* const* d_in, const int* in_sizes, int n_in,
                              void* d_out, int out_size, void* d_ws, size_t ws_size,
                              hipStream_t stream) {
    const float* x   = (const float*)d_in[0];
    const float* adj = (const float*)d_in[1];
    const float* W0  = (const float*)d_in[2];
    const float* b0  = (const float*)d_in[3];
    const float* W1  = (const float*)d_in[4];
    const float* b1  = (const float*)d_in[5];
    const float* W2  = (const float*)d_in[6];
    const float* b2  = (const float*)d_in[7];
    const float* Wo0 = (const float*)d_in[8];
    const float* bo0 = (const float*)d_in[9];
    const float* Wo1 = (const float*)d_in[10];
    const float* bo1 = (const float*)d_in[11];
    float* out = (float*)d_out;

    char* ws = (char*)d_ws;
    constexpr int S = 16;                    // k-splits (klen = 512)
    constexpr int KLEN = N / S;
    unsigned short* y_part = (unsigned short*)ws;                 // <= 16 MiB
    unsigned short* hT     = (unsigned short*)(ws + (16u << 20)); // 1 MiB
    unsigned char* adj_b   = (unsigned char*)(ws + (18u << 20));  // 64 MiB fp8
    const size_t NEED_FULL = ((size_t)18 << 20) + (size_t)N * N;
    const bool cache = ws_size >= NEED_FULL;

    lin0_kernel<<<512, 256, 0, stream>>>(x, W0, b0, hT);

    if (cache)
        agg_kernel<16, 128, 1><<<dim3(128, S), 256, 0, stream>>>(adj, nullptr, adj_b, hT, y_part, KLEN);
    else
        agg_kernel<16, 128, 0><<<dim3(128, S), 256, 0, stream>>>(adj, nullptr, nullptr, hT, y_part, KLEN);

    mid_linear_kernel<16, 32, S><<<512, 256, 0, stream>>>(y_part, W1, b1, hT);

    if (cache)
        agg_kernel<32, 64, 2><<<dim3(128, S), 256, 0, stream>>>(nullptr, adj_b, nullptr, hT, y_part, KLEN);
    else
        agg_kernel<32, 64, 0><<<dim3(128, S), 256, 0, stream>>>(adj, nullptr, nullptr, hT, y_part, KLEN);

    mid_linear_kernel<32, 64, S><<<512, 256, 0, stream>>>(y_part, W2, b2, hT);

    if (cache)
        agg_kernel<64, 64, 2><<<dim3(128, S), 256, 0, stream>>>(nullptr, adj_b, nullptr, hT, y_part, KLEN);
    else
        agg_kernel<64, 64, 0><<<dim3(128, S), 256, 0, stream>>>(adj, nullptr, nullptr, hT, y_part, KLEN);

    head_kernel<S><<<512, 256, 0, stream>>>(y_part, Wo0, bo0, Wo1, bo1, out);
}

// Round 11
// 128.693 us; speedup vs baseline: 1.1074x; 1.0175x over previous
//
#include <hip/hip_runtime.h>

#define N 8192

typedef __attribute__((ext_vector_type(8))) short short8;
typedef __attribute__((ext_vector_type(4))) float f32x4;
typedef __attribute__((ext_vector_type(2))) float f32x2;

#define ADJ_SC 4096.0f
#define ADJ_ISC (1.0f / 4096.0f)

__device__ __forceinline__ unsigned short f2bf(float f) {
    union { float f; unsigned int u; } v; v.f = f;
    unsigned int r = v.u + 0x7FFFu + ((v.u >> 16) & 1u);  // round-to-nearest-even
    return (unsigned short)(r >> 16);
}

__device__ __forceinline__ float bf2f(unsigned short u) {
    return __builtin_bit_cast(float, (unsigned int)u << 16);
}

__device__ __forceinline__ void gl2lds16(const void* g, void* l) {
    __builtin_amdgcn_global_load_lds(
        (const __attribute__((address_space(1))) unsigned int*)g,
        (__attribute__((address_space(3))) unsigned int*)l, 16, 0, 0);
}

// 8 fp8-e4m3 bytes -> 8 bf16 (lossless: every e4m3 value is exactly a bf16)
__device__ __forceinline__ short8 fp8x8_to_bf16x8(uint2 a8) {
    short8 r;
    #pragma unroll
    for (int d = 0; d < 2; ++d) {
        unsigned int src = (d == 0) ? a8.x : a8.y;
        f32x2 lo = __builtin_amdgcn_cvt_pk_f32_fp8(src, false);
        f32x2 hi = __builtin_amdgcn_cvt_pk_f32_fp8(src, true);
        r[4 * d + 0] = (short)(__builtin_bit_cast(unsigned int, lo[0]) >> 16);
        r[4 * d + 1] = (short)(__builtin_bit_cast(unsigned int, lo[1]) >> 16);
        r[4 * d + 2] = (short)(__builtin_bit_cast(unsigned int, hi[0]) >> 16);
        r[4 * d + 3] = (short)(__builtin_bit_cast(unsigned int, hi[1]) >> 16);
    }
    return r;
}

#define BAR_SCHED() do { __builtin_amdgcn_s_barrier(); \
                         __builtin_amdgcn_sched_barrier(0); } while (0)

// ---------------------------------------------------------------------------
// Aggregation: y_part[ks] = adj[rows, kslice] @ h   (partials stored bf16)
// MODE 0: adj f32 (no writeback)     [BK=128, counted-vmcnt reg prefetch]
// MODE 1: adj f32 + pre-swizzled fp8-e4m3 writeback (adj*4096)  [BK=128]
// MODE 2: linear gl2lds of pre-swizzled fp8 adj (BK=64), double-buffered,
//   lossless fp8->bf16 expand in regs, bf16 MFMA, acc *= 2^-12 at epilogue.
// hT stored PRE-SWIZZLED (elem ^ ((c&7)<<3)); adj_b pre-swizzled within
// 64-B k-chunks (byte ^ ((row&7)<<3)). LDS fragment reads apply same XOR.
// BM=64 rows, 4 waves, wave w -> rows [16w,16w+16).   (verbatim R10)
// ---------------------------------------------------------------------------
template<int NC, int BK, int MODE>
__global__ __launch_bounds__(256) void agg_kernel(
    const float* __restrict__ adj,
    const unsigned char* __restrict__ adj_b_in,
    unsigned char* __restrict__ adj_b_out,
    const unsigned short* __restrict__ hT,   // [NC][N] bf16, pre-swizzled
    unsigned short* __restrict__ y,          // [S][N][NC] bf16 partials
    int klen)
{
    constexpr int BM = 64;
    constexpr int NCT = NC / 16;

    const int tid = threadIdx.x;
    const int w  = tid >> 6;
    const int l  = tid & 63;
    const int hi = l >> 4;
    const int lr = l & 15;
    const int row0 = blockIdx.x * BM;
    const int k00  = blockIdx.y * klen;
    const int nt   = klen / BK;

    f32x4 acc[NCT];
    #pragma unroll
    for (int i = 0; i < NCT; ++i) acc[i] = f32x4{0.f, 0.f, 0.f, 0.f};

    if constexpr (MODE == 2) {
        // fp8 adj tile: BK bytes/row; bf16 hT tile: 2*BK bytes/row
        __shared__ unsigned char as2_[2][BM * BK];
        __shared__ unsigned short hs2_[2][NC * BK];
        constexpr int TA = (BM * BK) / 1024;       // 1KB chunks, adj tile
        constexpr int TH = (NC * 2 * BK) / 1024;   // 1KB chunks, hT tile
        constexpr int GRA = BK / 16, RPA = 1024 / BK;
        constexpr int GRH = (2 * BK) / 16, RPH = 1024 / (2 * BK);
        constexpr int KW = (TA + TH) / 4;          // per-wave gl2lds per stage

        auto stage = [&](char* ab, char* hb, int t) {
            const int kb = k00 + t * BK;
            #pragma unroll
            for (int i = w; i < TA; i += 4) {
                int r = i * RPA + l / GRA, g = l % GRA;
                gl2lds16(adj_b_in + (size_t)(row0 + r) * N + kb + 16 * g,
                         ab + i * 1024);
            }
            #pragma unroll
            for (int i = w; i < TH; i += 4) {
                int c = i * RPH + l / GRH, g = l % GRH;
                gl2lds16(hT + (size_t)c * N + kb + 8 * g, hb + i * 1024);
            }
        };

        stage((char*)as2_[0], (char*)hs2_[0], 0);
        for (int t = 0; t < nt; ++t) {
            char* ca = (char*)as2_[t & 1];
            char* ch = (char*)hs2_[t & 1];
            char* na = (char*)as2_[(t & 1) ^ 1];
            char* nh = (char*)hs2_[(t & 1) ^ 1];
            if (t + 1 < nt) {
                stage(na, nh, t + 1);
                asm volatile("s_waitcnt vmcnt(%0)" :: "n"(KW) : "memory");
            } else {
                asm volatile("s_waitcnt vmcnt(0)" ::: "memory");
            }
            BAR_SCHED();
            #pragma unroll
            for (int kk = 0; kk < BK; kk += 32) {
                const int arow = 16 * w + lr;
                uint2 a8 = *reinterpret_cast<const uint2*>(
                    ca + arow * BK + ((kk + 8 * hi) ^ ((arow & 7) << 3)));
                short8 a = fp8x8_to_bf16x8(a8);
                #pragma unroll
                for (int ct = 0; ct < NCT; ++ct) {
                    const int bcol = 16 * ct + lr;
                    short8 b = *reinterpret_cast<const short8*>(
                        ch + bcol * (2 * BK) + ((2 * kk + 16 * hi) ^ ((bcol & 7) << 4)));
                    acc[ct] = __builtin_amdgcn_mfma_f32_16x16x32_bf16(a, b, acc[ct], 0, 0, 0);
                }
            }
            asm volatile("s_waitcnt lgkmcnt(0)" ::: "memory");
            BAR_SCHED();
        }
        #pragma unroll
        for (int ct = 0; ct < NCT; ++ct)
            #pragma unroll
            for (int r = 0; r < 4; ++r) acc[ct][r] *= ADJ_ISC;
    } else {
        // MODE 0/1: BK==128. Counted-vmcnt reg-prefetch pipeline (R7-proven).
        __shared__ unsigned short as_[BM * BK];
        __shared__ unsigned short hs_[NC * BK];
        char* asb = (char*)as_;
        char* hsb = (char*)hs_;
        constexpr int ROWB = BK * 2;
        constexpr int LV = 8;
        constexpr int TH = (NC * ROWB) / 1024;
        float4 pf[LV];
        #pragma unroll
        for (int it = 0; it < LV; ++it) {
            int idx = tid + it * 256, r = idx >> 5, q = idx & 31;
            const f32x4* p = reinterpret_cast<const f32x4*>(
                adj + (size_t)(row0 + r) * N + k00 + 4 * q);
            f32x4 t0 = __builtin_nontemporal_load(p);
            pf[it] = float4{t0[0], t0[1], t0[2], t0[3]};
        }
        for (int t = 0; t < nt; ++t) {
            const int kb = k00 + t * BK;
            // (1) hT tile: linear gl2lds (content pre-swizzled)  [oldest]
            #pragma unroll
            for (int i = w; i < TH; i += 4) {
                int c = i * 4 + l / 16;   // 4 rows per 1KB chunk (ROWB=256)
                int g = l % 16;
                gl2lds16(hT + (size_t)c * N + kb + 8 * g, hsb + i * 1024);
            }
            __builtin_amdgcn_sched_barrier(0);
            // (2) convert + fp8 writeback store + swizzled bf16 LDS write
            #pragma unroll
            for (int it = 0; it < LV; ++it) {
                int idx = tid + it * 256, r = idx >> 5, q = idx & 31;
                ushort4 u;
                u.x = f2bf(pf[it].x); u.y = f2bf(pf[it].y);
                u.z = f2bf(pf[it].z); u.w = f2bf(pf[it].w);
                if (MODE == 1) {
                    unsigned int pk = 0;
                    pk = __builtin_amdgcn_cvt_pk_fp8_f32(
                        pf[it].x * ADJ_SC, pf[it].y * ADJ_SC, pk, false);
                    pk = __builtin_amdgcn_cvt_pk_fp8_f32(
                        pf[it].z * ADJ_SC, pf[it].w * ADJ_SC, pk, true);
                    *reinterpret_cast<unsigned int*>(
                        adj_b_out + (size_t)(row0 + r) * N + kb +
                        ((4 * q) ^ ((r & 7) << 3))) = pk;
                }
                *reinterpret_cast<ushort4*>(
                    asb + r * ROWB + ((8 * q) ^ ((r & 7) << 4))) = u;
            }
            __builtin_amdgcn_sched_barrier(0);
            // (3) next-tile prefetch [newest, stays in flight across barriers]
            if (t + 1 < nt) {
                #pragma unroll
                for (int it = 0; it < LV; ++it) {
                    int idx = tid + it * 256, r = idx >> 5, q = idx & 31;
                    const f32x4* p = reinterpret_cast<const f32x4*>(
                        adj + (size_t)(row0 + r) * N + kb + BK + 4 * q);
                    f32x4 t0 = __builtin_nontemporal_load(p);
                    pf[it] = float4{t0[0], t0[1], t0[2], t0[3]};
                }
                __builtin_amdgcn_sched_barrier(0);
                if (MODE == 1)
                    asm volatile("s_waitcnt vmcnt(16) lgkmcnt(0)" ::: "memory");
                else
                    asm volatile("s_waitcnt vmcnt(8) lgkmcnt(0)" ::: "memory");
            } else {
                if (MODE == 1)
                    asm volatile("s_waitcnt vmcnt(8) lgkmcnt(0)" ::: "memory");
                else
                    asm volatile("s_waitcnt vmcnt(0) lgkmcnt(0)" ::: "memory");
            }
            BAR_SCHED();
            // (4) MFMA phase
            #pragma unroll
            for (int kk = 0; kk < BK; kk += 32) {
                const int arow = 16 * w + lr;
                short8 a = *reinterpret_cast<const short8*>(
                    asb + arow * ROWB + ((2 * kk + 16 * hi) ^ ((arow & 7) << 4)));
                #pragma unroll
                for (int ct = 0; ct < NCT; ++ct) {
                    const int bcol = 16 * ct + lr;
                    short8 b = *reinterpret_cast<const short8*>(
                        hsb + bcol * ROWB + ((2 * kk + 16 * hi) ^ ((bcol & 7) << 4)));
                    acc[ct] = __builtin_amdgcn_mfma_f32_16x16x32_bf16(a, b, acc[ct], 0, 0, 0);
                }
            }
            asm volatile("s_waitcnt lgkmcnt(0)" ::: "memory");
            BAR_SCHED();
        }
    }
    // write bf16 partials: D layout col=lane&15, row=4*(lane>>4)+reg
    unsigned short* yp = y + (size_t)blockIdx.y * N * NC;
    #pragma unroll
    for (int ct = 0; ct < NCT; ++ct) {
        #pragma unroll
        for (int r = 0; r < 4; ++r) {
            yp[(size_t)(row0 + 16 * w + 4 * hi + r) * NC + 16 * ct + lr] =
                f2bf(acc[ct][r]);
        }
    }
}

// ---------------------------------------------------------------------------
// lin0: hT = bf16((x @ W0 + b0)^T), pre-swizzled columns. 16 rows/block.
// ---------------------------------------------------------------------------
__global__ __launch_bounds__(256) void lin0_kernel(
    const float* __restrict__ x, const float* __restrict__ W,
    const float* __restrict__ b, unsigned short* __restrict__ hT)
{
    __shared__ float xs[16][129];
    const int tid = threadIdx.x;
    const int row0 = blockIdx.x * 16;
    #pragma unroll
    for (int it = 0; it < 2; ++it) {
        int idx = tid + it * 256;             // 0..511 = 16 rows x 32 float4
        int r = idx >> 5, q = idx & 31;
        float4 v = *reinterpret_cast<const float4*>(x + (size_t)(row0 + r) * 128 + 4 * q);
        xs[r][4 * q + 0] = v.x; xs[r][4 * q + 1] = v.y;
        xs[r][4 * q + 2] = v.z; xs[r][4 * q + 3] = v.w;
    }
    __syncthreads();
    const int r = tid & 15, c = tid >> 4;     // 16 rows x 16 cols
    float acc = b[c];
    #pragma unroll 4
    for (int k = 0; k < 128; ++k) acc += xs[r][k] * W[k * 16 + c];
    hT[(size_t)c * N + ((row0 + r) ^ ((c & 7) << 3))] = f2bf(acc);
}

// ---------------------------------------------------------------------------
// mid linear: hT = bf16((relu(sum_s y_s) @ W + b)^T), pre-swizzled columns.
// 16 rows/block -> 512 blocks.
// ---------------------------------------------------------------------------
template<int NIN, int NOUT, int S>
__global__ __launch_bounds__(256) void mid_linear_kernel(
    const unsigned short* __restrict__ y,  // [S][N][NIN] bf16
    const float* __restrict__ W,           // [NIN][NOUT]
    const float* __restrict__ b,
    unsigned short* __restrict__ hT)       // [NOUT][N]
{
    __shared__ float xs[16][NIN + 1];
    const int tid = threadIdx.x;
    const int row0 = blockIdx.x * 16;
    constexpr int NF4 = 16 * NIN / 4;      // 64 / 128 / 256
    if (tid < NF4) {
        int r = tid / (NIN / 4), q = tid % (NIN / 4);
        size_t off = (size_t)(row0 + r) * NIN + 4 * q;
        float s0 = 0.f, s1 = 0.f, s2 = 0.f, s3 = 0.f;
        #pragma unroll
        for (int s = 0; s < S; ++s) {
            ushort4 t = *reinterpret_cast<const ushort4*>(
                y + (size_t)s * N * NIN + off);
            s0 += bf2f(t.x); s1 += bf2f(t.y);
            s2 += bf2f(t.z); s3 += bf2f(t.w);
        }
        xs[r][4 * q + 0] = fmaxf(s0, 0.f);
        xs[r][4 * q + 1] = fmaxf(s1, 0.f);
        xs[r][4 * q + 2] = fmaxf(s2, 0.f);
        xs[r][4 * q + 3] = fmaxf(s3, 0.f);
    }
    __syncthreads();
    const int r = tid & 15, c0 = tid >> 4;   // 16 rows x 16 col-slots
    constexpr int CC = NOUT / 16;
    float acc[CC];
    #pragma unroll
    for (int cc = 0; cc < CC; ++cc) acc[cc] = b[c0 + 16 * cc];
    for (int k = 0; k < NIN; ++k) {
        float xv = xs[r][k];
        #pragma unroll
        for (int cc = 0; cc < CC; ++cc) acc[cc] += xv * W[k * NOUT + c0 + 16 * cc];
    }
    #pragma unroll
    for (int cc = 0; cc < CC; ++cc) {
        int c = c0 + 16 * cc;
        hT[(size_t)c * N + ((row0 + r) ^ ((c & 7) << 3))] = f2bf(acc[cc]);
    }
}

// ---------------------------------------------------------------------------
// head: out = relu(relu(sum_s y_s) @ Wo0 + bo0) @ Wo1 + bo1, 16 rows/block
// ---------------------------------------------------------------------------
template<int S>
__global__ __launch_bounds__(256) void head_kernel(
    const unsigned short* __restrict__ y,  // [S][N][64] bf16
    const float* __restrict__ Wo0, const float* __restrict__ bo0,
    const float* __restrict__ Wo1, const float* __restrict__ bo1,
    float* __restrict__ out)
{
    __shared__ float xr[16][68];
    __shared__ float hid[16][36];
    const int tid = threadIdx.x;
    const int row0 = blockIdx.x * 16;
    {
        int r = tid >> 4, q = tid & 15;
        size_t off = (size_t)(row0 + r) * 64 + 4 * q;
        float s0 = 0.f, s1 = 0.f, s2 = 0.f, s3 = 0.f;
        #pragma unroll
        for (int s = 0; s < S; ++s) {
            ushort4 t = *reinterpret_cast<const ushort4*>(
                y + (size_t)s * N * 64 + off);
            s0 += bf2f(t.x); s1 += bf2f(t.y);
            s2 += bf2f(t.z); s3 += bf2f(t.w);
        }
        xr[r][4 * q + 0] = fmaxf(s0, 0.f);
        xr[r][4 * q + 1] = fmaxf(s1, 0.f);
        xr[r][4 * q + 2] = fmaxf(s2, 0.f);
        xr[r][4 * q + 3] = fmaxf(s3, 0.f);
    }
    __syncthreads();
    {
        int j = tid & 31, r0 = tid >> 5;
        #pragma unroll
        for (int rr = r0; rr < 16; rr += 8) {
            float a = bo0[j];
            #pragma unroll
            for (int k = 0; k < 64; ++k) a += xr[rr][k] * Wo0[k * 32 + j];
            hid[rr][j] = fmaxf(a, 0.f);
        }
    }
    __syncthreads();
    if (tid < 160) {
        int r = tid / 10, c = tid % 10;
        float a = bo1[c];
        #pragma unroll
        for (int k = 0; k < 32; ++k) a += hid[r][k] * Wo1[k * 10 + c];
        out[(size_t)(row0 + r) * 10 + c] = a;
    }
}

extern "C" void kernel_launch(void* const* d_in, const int* in_sizes, int n_in,
                              void* d_out, int out_size, void* d_ws, size_t ws_size,
                              hipStream_t stream) {
    const float* x   = (const float*)d_in[0];
    const float* adj = (const float*)d_in[1];
    const float* W0  = (const float*)d_in[2];
    const float* b0  = (const float*)d_in[3];
    const float* W1  = (const float*)d_in[4];
    const float* b1  = (const float*)d_in[5];
    const float* W2  = (const float*)d_in[6];
    const float* b2  = (const float*)d_in[7];
    const float* Wo0 = (const float*)d_in[8];
    const float* bo0 = (const float*)d_in[9];
    const float* Wo1 = (const float*)d_in[10];
    const float* bo1 = (const float*)d_in[11];
    float* out = (float*)d_out;

    char* ws = (char*)d_ws;
    constexpr int S1 = 16;                   // k-splits agg1 (klen = 512)
    constexpr int S2 = 8;                    // k-splits agg2/3 (klen = 1024)
    unsigned short* y_part = (unsigned short*)ws;                 // <= 8 MiB
    unsigned short* hT     = (unsigned short*)(ws + (16u << 20)); // 1 MiB
    unsigned char* adj_b   = (unsigned char*)(ws + (18u << 20));  // 64 MiB fp8
    const size_t NEED_FULL = ((size_t)18 << 20) + (size_t)N * N;
    const bool cache = ws_size >= NEED_FULL;

    lin0_kernel<<<512, 256, 0, stream>>>(x, W0, b0, hT);

    if (cache)
        agg_kernel<16, 128, 1><<<dim3(128, S1), 256, 0, stream>>>(adj, nullptr, adj_b, hT, y_part, N / S1);
    else
        agg_kernel<16, 128, 0><<<dim3(128, S1), 256, 0, stream>>>(adj, nullptr, nullptr, hT, y_part, N / S1);

    mid_linear_kernel<16, 32, S1><<<512, 256, 0, stream>>>(y_part, W1, b1, hT);

    if (cache)
        agg_kernel<32, 64, 2><<<dim3(128, S2), 256, 0, stream>>>(nullptr, adj_b, nullptr, hT, y_part, N / S2);
    else
        agg_kernel<32, 64, 0><<<dim3(128, S2), 256, 0, stream>>>(adj, nullptr, nullptr, hT, y_part, N / S2);

    mid_linear_kernel<32, 64, S2><<<512, 256, 0, stream>>>(y_part, W2, b2, hT);

    if (cache)
        agg_kernel<64, 64, 2><<<dim3(128, S2), 256, 0, stream>>>(nullptr, adj_b, nullptr, hT, y_part, N / S2);
    else
        agg_kernel<64, 64, 0><<<dim3(128, S2), 256, 0, stream>>>(adj, nullptr, nullptr, hT, y_part, N / S2);

    head_kernel<S2><<<512, 256, 0, stream>>>(y_part, Wo0, bo0, Wo1, bo1, out);
}